// Round 7
// baseline (284.581 us; speedup 1.0000x reference)
//
#include <hip/hip_runtime.h>
#include <hip/hip_bf16.h>

#define Bq   32
#define Cq   64
#define NPq  192
#define NOq  72
#define PTS  (NPq * NOq)   // 13824
#define REGD 76
#define OUTD 79
#define HSTR 68            // padded activation-row stride (words)

typedef __attribute__((ext_vector_type(8))) short short8;
typedef __attribute__((ext_vector_type(4))) float float4v;

__device__ inline unsigned short f2bf(float x) {
    __hip_bfloat16 h = __float2bfloat16(x);
    return *reinterpret_cast<unsigned short*>(&h);
}
__device__ inline float bf2f(unsigned short u) {
    unsigned int x = ((unsigned int)u) << 16;
    float f;
    __builtin_memcpy(&f, &x, 4);
    return f;
}

// ---------------------------------------------------------------------------
// Phase 0 (once): build gated y-blended tables for ALL 3 stages.
// tab[s][b][o][x][c] bf16, x in [0..W] (x=W replicates W-1), c innermost.
// One column (o,x) = 128 B = all 64 channels.  Block = (stage, b, o).
// ---------------------------------------------------------------------------
__global__ __launch_bounds__(256) void build_tables_kernel(
    const float* __restrict__ f0,   // x2: H=10,W=25
    const float* __restrict__ f1,   // x1: H=20,W=50
    const float* __restrict__ f2,   // x0: H=40,W=100
    const float* __restrict__ lw,
    unsigned short* __restrict__ t0,
    unsigned short* __restrict__ t1,
    unsigned short* __restrict__ t2)
{
    __shared__ float sRow[64 * 101];

    const int tid = threadIdx.x;
    int bid = blockIdx.x;
    const float* feat; unsigned short* tab; int H, W;
    if (bid < 2304)      { feat = f0; tab = t0; H = 10; W = 25; }
    else if (bid < 4608) { feat = f1; tab = t1; H = 20; W = 50;  bid -= 2304; }
    else                 { feat = f2; tab = t2; H = 40; W = 100; bid -= 4608; }
    const int b = bid / NOq;
    const int o = bid - b * NOq;
    const int Wp = W + 1;

    const float ys = 1.0f - (float)o * (1.0f / 71.0f);
    const float iy = ys * (float)(H - 1);
    const float fy = floorf(iy);
    const float wy = iy - fy;
    int iy0 = (int)fy; iy0 = iy0 < 0 ? 0 : (iy0 > H - 1 ? H - 1 : iy0);
    const int iy1 = (iy0 + 1 > H - 1) ? H - 1 : iy0 + 1;
    const float gate = 1.0f / (1.0f + __expf(-lw[o]));

    const float* fb = feat + (size_t)b * 64 * H * W;
    const int iy0W = iy0 * W, iy1W = iy1 * W;

    // blend rows -> LDS [c][x] fp32 (padded stride Wp: conflict-light)
    const int tot = 64 * W;
    for (int idx = tid; idx < tot; idx += 256) {
        const int c = idx / W;
        const int x = idx - c * W;
        const float* f = fb + c * (H * W);
        sRow[c * Wp + x] = ((1.0f - wy) * f[iy0W + x] + wy * f[iy1W + x]) * gate;
    }
    __syncthreads();

    // write transposed [x][c] bf16 (c-major coalesced), pad x=W
    unsigned short* to = tab + (size_t)(b * NOq + o) * Wp * 64;
    const int tot2 = Wp * 64;
    for (int idx = tid; idx < tot2; idx += 256) {
        const int x = idx >> 6;
        const int c = idx & 63;
        const int xx = (x < W) ? x : (W - 1);
        to[idx] = f2bf(sRow[c * Wp + xx]);
    }
}

// ---------------------------------------------------------------------------
// Phase 1+2 fused: gather from table (L2) + x-lerp in-register + MFMA +
// relu/pairmax/mean epilogue.  Block = (b, group of 8 n); wave owns an
// n-pair (9 tiles).  No LDS.
// ---------------------------------------------------------------------------
template<int W>
__global__ __launch_bounds__(256) void fused_pool_kernel(
    const unsigned short* __restrict__ tab,   // [B][72][W+1][64] bf16
    const float* __restrict__ xsrc, const int xstride,
    const float* __restrict__ lsgi,           // [64][64] this stage
    float* __restrict__ sumFeat,              // [B*NP][64]
    const int accumulate)
{
    constexpr int Wp = W + 1;
    const int tid  = threadIdx.x;
    const int w    = tid >> 6;
    const int lane = tid & 63;
    const int b    = blockIdx.x / 24;
    const int ng   = blockIdx.x - b * 24;
    const int npair = ng * 4 + w;             // 0..95

    // build W B-frags: wf[dt][ks] (same as verified R6 layout)
    short8 wf[4][2];
    {
        const int kb = ((lane >> 4) & 3) * 8;
        const int dl = lane & 15;
        #pragma unroll
        for (int ks = 0; ks < 2; ++ks)
            #pragma unroll
            for (int dt = 0; dt < 4; ++dt) {
                union { unsigned short u[8]; short8 v; } pk;
                #pragma unroll
                for (int j = 0; j < 8; ++j)
                    pk.u[j] = f2bf(lsgi[(ks * 32 + kb + j) * 64 + dt * 16 + dl]);
                wf[dt][ks] = pk.v;
            }
    }

    const unsigned short* tb = tab + (size_t)b * NOq * Wp * 64;
    const float* xp = xsrc + (size_t)xstride * b;
    const int m  = lane & 15;
    const int kg = lane >> 4;
    const int nt0 = npair * 9;

    float sums0[4] = {0.f, 0.f, 0.f, 0.f};
    float sums1[4] = {0.f, 0.f, 0.f, 0.f};

    #pragma unroll
    for (int ntl = 0; ntl < 9; ++ntl) {
        const int pt = (nt0 + ntl) * 16 + m;
        const int o  = pt % NOq;
        float ixf = xp[pt] * (float)(W - 1);
        ixf = fminf(fmaxf(ixf, 0.0f), (float)(W - 1));
        const float fx = floorf(ixf);
        const float wx = ixf - fx;
        const int ix0 = (int)fx;

        const unsigned short* col = tb + ((size_t)o * Wp + ix0) * 64 + kg * 8;
        union { unsigned short u[8]; short8 v; } t00, t01, t10, t11, a0, a1;
        t00.v = *(const short8*)(col);           // x0, k = kg*8..
        t01.v = *(const short8*)(col + 64);      // x1, k = kg*8..
        t10.v = *(const short8*)(col + 32);      // x0, k = 32+kg*8..
        t11.v = *(const short8*)(col + 96);      // x1, k = 32+kg*8..
        #pragma unroll
        for (int j = 0; j < 8; ++j) {
            const float l0 = bf2f(t00.u[j]), h0 = bf2f(t01.u[j]);
            const float l1 = bf2f(t10.u[j]), h1 = bf2f(t11.u[j]);
            a0.u[j] = f2bf(l0 + wx * (h0 - l0));
            a1.u[j] = f2bf(l1 + wx * (h1 - l1));
        }

        const bool hi = (ntl * 16 + (kg * 4)) >= NOq;
        #pragma unroll
        for (int dt = 0; dt < 4; ++dt) {
            float4v c = {0.f, 0.f, 0.f, 0.f};
            c = __builtin_amdgcn_mfma_f32_16x16x32_bf16(a0.v, wf[dt][0], c, 0, 0, 0);
            c = __builtin_amdgcn_mfma_f32_16x16x32_bf16(a1.v, wf[dt][1], c, 0, 0, 0);
            const float pm0 = fmaxf(fmaxf(c[0], c[1]), 0.f);
            const float pm1 = fmaxf(fmaxf(c[2], c[3]), 0.f);
            const float add = pm0 + pm1;
            if (hi) sums1[dt] += add; else sums0[dt] += add;
        }
    }

    #pragma unroll
    for (int dt = 0; dt < 4; ++dt) {
        float v0 = sums0[dt], v1 = sums1[dt];
        v0 += __shfl_xor(v0, 16); v0 += __shfl_xor(v0, 32);
        v1 += __shfl_xor(v1, 16); v1 += __shfl_xor(v1, 32);
        sums0[dt] = v0; sums1[dt] = v1;
    }

    if (lane < 16) {
        const size_t row0 = (size_t)(b * NPq + npair * 2) * 64;
        #pragma unroll
        for (int dt = 0; dt < 4; ++dt) {
            const int d = dt * 16 + lane;
            float t0 = sums0[dt] * (1.0f / 36.0f);
            float t1 = sums1[dt] * (1.0f / 36.0f);
            float* p0 = sumFeat + row0 + d;
            float* p1 = sumFeat + row0 + 64 + d;
            if (accumulate) { t0 += *p0; t1 += *p1; }
            *p0 = t0; *p1 = t1;
        }
    }
}

// ---------------------------------------------------------------------------
// Phase 3: heads (verbatim from R6 — verified).  Block = (32 points, branch).
// ---------------------------------------------------------------------------
__global__ __launch_bounds__(256) void head_kernel(
    const float* __restrict__ sumFeat, const float invS,
    const float* __restrict__ fc_w,  const float* __restrict__ fc_b,
    const float* __restrict__ cls_w, const float* __restrict__ cls_b,
    const float* __restrict__ cls_ow, const float* __restrict__ cls_ob,
    const float* __restrict__ reg_w, const float* __restrict__ reg_b,
    const float* __restrict__ reg_ow, const float* __restrict__ reg_ob,
    const float* __restrict__ loc_w, const float* __restrict__ loc_b,
    const float* __restrict__ loc_ow, const float* __restrict__ loc_ob,
    float* __restrict__ out, float* __restrict__ xs_next)
{
    __shared__ __align__(16) float sAct0[32 * HSTR];
    __shared__ __align__(16) float sAct1[32 * HSTR];
    __shared__ __align__(16) float sW0[4096];
    __shared__ __align__(16) float sW1[4864];

    const int tid = threadIdx.x;
    const int hb  = blockIdx.x % 3;
    const int pg  = blockIdx.x / 3;
    const int p0  = pg * 32;
    const int tm  = tid >> 4;
    const int tn  = tid & 15;

    const float* h_w  = (hb == 0) ? cls_w  : (hb == 1) ? reg_w  : loc_w;
    const float* h_b  = (hb == 0) ? cls_b  : (hb == 1) ? reg_b  : loc_b;
    const float* h_ow = (hb == 0) ? cls_ow : (hb == 1) ? reg_ow : loc_ow;
    const float* h_ob = (hb == 0) ? cls_ob : (hb == 1) ? reg_ob : loc_ob;
    const int ow_n    = (hb == 0) ? 128    : (hb == 1) ? 64 * REGD : 64;

    #pragma unroll
    for (int i = 0; i < 4; ++i)
        *(float4*)&sW0[(i * 256 + tid) * 4] = *(const float4*)&fc_w[(i * 256 + tid) * 4];
    for (int idx = tid; idx < 32 * 64; idx += 256) {
        const int p = idx >> 6, c = idx & 63;
        sAct0[p * HSTR + c] = sumFeat[(size_t)(p0 + p) * 64 + c] * invS;
    }

    auto do_gemm = [&](const float* src, float* dst, const float* wbuf,
                       const float* gb, const float* nextw, int nextn,
                       float* nextbuf) {
        __syncthreads();
        float4 pf[5];
        const int n4 = nextn >> 2;
        #pragma unroll
        for (int i = 0; i < 5; ++i) {
            const int idx = i * 256 + tid;
            if (idx < n4) pf[i] = *(const float4*)&nextw[idx * 4];
        }
        const float4 b4 = *(const float4*)&gb[4 * tn];
        float4 acc0 = b4, acc1 = b4;
        const float* r0 = src + (2 * tm) * HSTR;
        const float* r1 = r0 + HSTR;
        #pragma unroll 4
        for (int k4 = 0; k4 < 16; ++k4) {
            const float4 a0 = *(const float4*)&r0[4 * k4];
            const float4 a1 = *(const float4*)&r1[4 * k4];
            const float4 w0 = *(const float4*)&wbuf[(4 * k4 + 0) * 64 + 4 * tn];
            const float4 w1 = *(const float4*)&wbuf[(4 * k4 + 1) * 64 + 4 * tn];
            const float4 w2 = *(const float4*)&wbuf[(4 * k4 + 2) * 64 + 4 * tn];
            const float4 w3 = *(const float4*)&wbuf[(4 * k4 + 3) * 64 + 4 * tn];
            acc0.x += a0.x*w0.x + a0.y*w1.x + a0.z*w2.x + a0.w*w3.x;
            acc0.y += a0.x*w0.y + a0.y*w1.y + a0.z*w2.y + a0.w*w3.y;
            acc0.z += a0.x*w0.z + a0.y*w1.z + a0.z*w2.z + a0.w*w3.z;
            acc0.w += a0.x*w0.w + a0.y*w1.w + a0.z*w2.w + a0.w*w3.w;
            acc1.x += a1.x*w0.x + a1.y*w1.x + a1.z*w2.x + a1.w*w3.x;
            acc1.y += a1.x*w0.y + a1.y*w1.y + a1.z*w2.y + a1.w*w3.y;
            acc1.z += a1.x*w0.z + a1.y*w1.z + a1.z*w2.z + a1.w*w3.z;
            acc1.w += a1.x*w0.w + a1.y*w1.w + a1.z*w2.w + a1.w*w3.w;
        }
        float4 v0, v1;
        v0.x = fmaxf(acc0.x, 0.f); v0.y = fmaxf(acc0.y, 0.f);
        v0.z = fmaxf(acc0.z, 0.f); v0.w = fmaxf(acc0.w, 0.f);
        v1.x = fmaxf(acc1.x, 0.f); v1.y = fmaxf(acc1.y, 0.f);
        v1.z = fmaxf(acc1.z, 0.f); v1.w = fmaxf(acc1.w, 0.f);
        *(float4*)&dst[(2 * tm) * HSTR + 4 * tn]     = v0;
        *(float4*)&dst[(2 * tm + 1) * HSTR + 4 * tn] = v1;
        #pragma unroll
        for (int i = 0; i < 5; ++i) {
            const int idx = i * 256 + tid;
            if (idx < n4) *(float4*)&nextbuf[idx * 4] = pf[i];
        }
    };

    do_gemm(sAct0, sAct1, sW0, fc_b,      h_w,        4096, sW1);
    do_gemm(sAct1, sAct0, sW1, h_b,       h_w + 4096, 4096, sW0);
    do_gemm(sAct0, sAct1, sW0, h_b + 64,  h_ow,       ow_n, sW1);
    __syncthreads();

    if (hb == 0) {
        if (tid < 64) {
            const int p = tid >> 1, d = tid & 1;
            const float* row = &sAct1[p * HSTR];
            float z = h_ob[d];
            #pragma unroll 4
            for (int k4 = 0; k4 < 16; ++k4) {
                const float4 a = *(const float4*)&row[4 * k4];
                z += a.x * sW1[(4 * k4 + 0) * 2 + d] + a.y * sW1[(4 * k4 + 1) * 2 + d]
                   + a.z * sW1[(4 * k4 + 2) * 2 + d] + a.w * sW1[(4 * k4 + 3) * 2 + d];
            }
            out[(size_t)(p0 + p) * OUTD + d] = z;
        }
    } else if (hb == 1) {
        const int p  = tid & 31;
        const int jg = tid >> 5;
        const float* row = &sAct1[p * HSTR];
        float* orow = out + (size_t)(p0 + p) * OUTD;
        float* xsp  = xs_next + (size_t)(p0 + p) * NOq;
        for (int j = jg; j < REGD; j += 8) {
            float z = h_ob[j];
            #pragma unroll 4
            for (int k4 = 0; k4 < 16; ++k4) {
                const float4 a = *(const float4*)&row[4 * k4];
                z += a.x * sW1[(4 * k4 + 0) * REGD + j] + a.y * sW1[(4 * k4 + 1) * REGD + j]
                   + a.z * sW1[(4 * k4 + 2) * REGD + j] + a.w * sW1[(4 * k4 + 3) * REGD + j];
            }
            orow[2 + j] = z;
            if (j >= 4) xsp[j - 4] = 1.0f / (1.0f + __expf(-z));
        }
    } else {
        if (tid < 32) {
            const float* row = &sAct1[tid * HSTR];
            float z = h_ob[0];
            #pragma unroll 4
            for (int k4 = 0; k4 < 16; ++k4) {
                const float4 a = *(const float4*)&row[4 * k4];
                z += a.x * sW1[4 * k4] + a.y * sW1[4 * k4 + 1]
                   + a.z * sW1[4 * k4 + 2] + a.w * sW1[4 * k4 + 3];
            }
            out[(size_t)(p0 + tid) * OUTD + 78] = z;
        }
    }
}

// ---------------------------------------------------------------------------
extern "C" void kernel_launch(void* const* d_in, const int* in_sizes, int n_in,
                              void* d_out, int out_size, void* d_ws, size_t ws_size,
                              hipStream_t stream)
{
    const float* x0        = (const float*)d_in[0];
    const float* x1        = (const float*)d_in[1];
    const float* x2        = (const float*)d_in[2];
    const float* prior_xs0 = (const float*)d_in[3];
    const float* l_weight  = (const float*)d_in[4];
    const float* lsgi_w    = (const float*)d_in[5];
    const float* fc_w      = (const float*)d_in[6];
    const float* fc_b      = (const float*)d_in[7];
    const float* cls_w     = (const float*)d_in[8];
    const float* cls_b     = (const float*)d_in[9];
    const float* cls_ow    = (const float*)d_in[10];
    const float* cls_ob    = (const float*)d_in[11];
    const float* reg_w     = (const float*)d_in[12];
    const float* reg_b     = (const float*)d_in[13];
    const float* reg_ow    = (const float*)d_in[14];
    const float* reg_ob    = (const float*)d_in[15];
    const float* loc_w     = (const float*)d_in[16];
    const float* loc_b     = (const float*)d_in[17];
    const float* loc_ow    = (const float*)d_in[18];
    const float* loc_ob    = (const float*)d_in[19];

    float* out     = (float*)d_out;
    float* sumFeat = (float*)d_ws;                               // [6144][64] f32
    float* xs      = sumFeat + (size_t)Bq * NPq * Cq;            // [6144][72] f32
    unsigned short* tab0 = (unsigned short*)(xs + (size_t)Bq * PTS);
    unsigned short* tab1 = tab0 + (size_t)Bq * NOq * 26  * 64;   // W=25
    unsigned short* tab2 = tab1 + (size_t)Bq * NOq * 51  * 64;   // W=50
    // tab2 size: Bq*NOq*101*64                                   // W=100

    hipLaunchKernelGGL(build_tables_kernel, dim3(3 * Bq * NOq), dim3(256), 0, stream,
                       x2, x1, x0, l_weight, tab0, tab1, tab2);

    for (int s = 0; s < 3; ++s) {
        const float* xsrc = (s == 0) ? prior_xs0 : xs;
        const int xstr    = (s == 0) ? 0 : PTS;
        if (s == 0)
            hipLaunchKernelGGL((fused_pool_kernel<25>), dim3(Bq * 24), dim3(256), 0, stream,
                               tab0, xsrc, xstr, lsgi_w + s * 4096, sumFeat, 0);
        else if (s == 1)
            hipLaunchKernelGGL((fused_pool_kernel<50>), dim3(Bq * 24), dim3(256), 0, stream,
                               tab1, xsrc, xstr, lsgi_w + s * 4096, sumFeat, 1);
        else
            hipLaunchKernelGGL((fused_pool_kernel<100>), dim3(Bq * 24), dim3(256), 0, stream,
                               tab2, xsrc, xstr, lsgi_w + s * 4096, sumFeat, 1);

        hipLaunchKernelGGL(head_kernel, dim3((Bq * NPq / 32) * 3), dim3(256), 0, stream,
                           sumFeat, 1.0f / (float)(s + 1),
                           fc_w, fc_b, cls_w, cls_b, cls_ow, cls_ob,
                           reg_w, reg_b, reg_ow, reg_ob,
                           loc_w, loc_b, loc_ow, loc_ob,
                           out + (size_t)s * Bq * NPq * OUTD, xs);
    }
}

// Round 8
// 279.607 us; speedup vs baseline: 1.0178x; 1.0178x over previous
//
#include <hip/hip_runtime.h>
#include <hip/hip_bf16.h>

#define Bq   32
#define Cq   64
#define NPq  192
#define NOq  72
#define PTS  (NPq * NOq)   // 13824
#define REGD 76
#define OUTD 79
#define HSTR 68            // padded activation-row stride (words)

typedef __attribute__((ext_vector_type(8))) short short8;
typedef __attribute__((ext_vector_type(4))) float float4v;

__device__ inline unsigned short f2bf(float x) {
    __hip_bfloat16 h = __float2bfloat16(x);
    return *reinterpret_cast<unsigned short*>(&h);
}
__device__ inline float bf2f(unsigned short u) {
    unsigned int x = ((unsigned int)u) << 16;
    float f;
    __builtin_memcpy(&f, &x, 4);
    return f;
}

// ---------------------------------------------------------------------------
// Phase 0 (once): build gated y-blended tables for ALL 3 stages.
// tab[s][b][o][x][c] bf16, x in [0..W] (x=W replicates W-1), c innermost.
// Block index is o-MAJOR: idx = o*96 + (s*32+b), so all 72 o-blocks of one
// (s,b) are ≡ same value mod 8 -> same XCD -> y-rows fetched from HBM once.
// ---------------------------------------------------------------------------
__global__ __launch_bounds__(256) void build_tables_kernel(
    const float* __restrict__ f0,   // x2: H=10,W=25
    const float* __restrict__ f1,   // x1: H=20,W=50
    const float* __restrict__ f2,   // x0: H=40,W=100
    const float* __restrict__ lw,
    unsigned short* __restrict__ t0,
    unsigned short* __restrict__ t1,
    unsigned short* __restrict__ t2)
{
    __shared__ float sRow[64 * 101];

    const int tid = threadIdx.x;
    const int o   = blockIdx.x / 96;
    const int sb  = blockIdx.x - o * 96;
    const int s   = sb >> 5;
    const int b   = sb & 31;

    const float* feat; unsigned short* tab; int H, W;
    if (s == 0)      { feat = f0; tab = t0; H = 10; W = 25; }
    else if (s == 1) { feat = f1; tab = t1; H = 20; W = 50; }
    else             { feat = f2; tab = t2; H = 40; W = 100; }
    const int Wp = W + 1;

    const float ys = 1.0f - (float)o * (1.0f / 71.0f);
    const float iy = ys * (float)(H - 1);
    const float fy = floorf(iy);
    const float wy = iy - fy;
    int iy0 = (int)fy; iy0 = iy0 < 0 ? 0 : (iy0 > H - 1 ? H - 1 : iy0);
    const int iy1 = (iy0 + 1 > H - 1) ? H - 1 : iy0 + 1;
    const float gate = 1.0f / (1.0f + __expf(-lw[o]));

    const float* fb = feat + (size_t)b * 64 * H * W;
    const int iy0W = iy0 * W, iy1W = iy1 * W;

    // blend rows -> LDS [c][x] fp32
    const int tot = 64 * W;
    for (int idx = tid; idx < tot; idx += 256) {
        const int c = idx / W;
        const int x = idx - c * W;
        const float* f = fb + c * (H * W);
        sRow[c * Wp + x] = ((1.0f - wy) * f[iy0W + x] + wy * f[iy1W + x]) * gate;
    }
    __syncthreads();

    // write transposed [x][c] bf16 (c-major coalesced), pad x=W
    unsigned short* to = tab + (size_t)(b * NOq + o) * Wp * 64;
    const int tot2 = Wp * 64;
    for (int idx = tid; idx < tot2; idx += 256) {
        const int x = idx >> 6;
        const int c = idx & 63;
        const int xx = (x < W) ? x : (W - 1);
        to[idx] = f2bf(sRow[c * Wp + xx]);
    }
}

// ---------------------------------------------------------------------------
// Phase 1+2 fused: gather from table (L2) + x-lerp in-register + MFMA +
// relu/pairmax/mean epilogue.  Block index = ng*32 + b so all 24 blocks of a
// batch land on XCD (b mod 8) -- the same XCD that built that batch's table.
// ---------------------------------------------------------------------------
template<int W>
__global__ __launch_bounds__(256) void fused_pool_kernel(
    const unsigned short* __restrict__ tab,   // [B][72][W+1][64] bf16
    const float* __restrict__ xsrc, const int xstride,
    const float* __restrict__ lsgi,           // [64][64] this stage
    float* __restrict__ sumFeat,              // [B*NP][64]
    const int accumulate)
{
    constexpr int Wp = W + 1;
    const int tid  = threadIdx.x;
    const int w    = tid >> 6;
    const int lane = tid & 63;
    const int ng   = blockIdx.x >> 5;         // 0..23
    const int b    = blockIdx.x & 31;
    const int npair = ng * 4 + w;             // 0..95

    // build W B-frags: wf[dt][ks]
    short8 wf[4][2];
    {
        const int kb = ((lane >> 4) & 3) * 8;
        const int dl = lane & 15;
        #pragma unroll
        for (int ks = 0; ks < 2; ++ks)
            #pragma unroll
            for (int dt = 0; dt < 4; ++dt) {
                union { unsigned short u[8]; short8 v; } pk;
                #pragma unroll
                for (int j = 0; j < 8; ++j)
                    pk.u[j] = f2bf(lsgi[(ks * 32 + kb + j) * 64 + dt * 16 + dl]);
                wf[dt][ks] = pk.v;
            }
    }

    const unsigned short* tb = tab + (size_t)b * NOq * Wp * 64;
    const float* xp = xsrc + (size_t)xstride * b;
    const int m  = lane & 15;
    const int kg = lane >> 4;
    const int nt0 = npair * 9;

    float sums0[4] = {0.f, 0.f, 0.f, 0.f};
    float sums1[4] = {0.f, 0.f, 0.f, 0.f};

    #pragma unroll
    for (int ntl = 0; ntl < 9; ++ntl) {
        const int pt = (nt0 + ntl) * 16 + m;
        const int o  = pt % NOq;
        float ixf = xp[pt] * (float)(W - 1);
        ixf = fminf(fmaxf(ixf, 0.0f), (float)(W - 1));
        const float fx = floorf(ixf);
        const float wx = ixf - fx;
        const int ix0 = (int)fx;

        const unsigned short* col = tb + ((size_t)o * Wp + ix0) * 64 + kg * 8;
        union { unsigned short u[8]; short8 v; } t00, t01, t10, t11, a0, a1;
        t00.v = *(const short8*)(col);           // x0, k = kg*8..
        t01.v = *(const short8*)(col + 64);      // x1, k = kg*8..
        t10.v = *(const short8*)(col + 32);      // x0, k = 32+kg*8..
        t11.v = *(const short8*)(col + 96);      // x1, k = 32+kg*8..
        #pragma unroll
        for (int j = 0; j < 8; ++j) {
            const float l0 = bf2f(t00.u[j]), h0 = bf2f(t01.u[j]);
            const float l1 = bf2f(t10.u[j]), h1 = bf2f(t11.u[j]);
            a0.u[j] = f2bf(l0 + wx * (h0 - l0));
            a1.u[j] = f2bf(l1 + wx * (h1 - l1));
        }

        const bool hi = (ntl * 16 + (kg * 4)) >= NOq;
        #pragma unroll
        for (int dt = 0; dt < 4; ++dt) {
            float4v c = {0.f, 0.f, 0.f, 0.f};
            c = __builtin_amdgcn_mfma_f32_16x16x32_bf16(a0.v, wf[dt][0], c, 0, 0, 0);
            c = __builtin_amdgcn_mfma_f32_16x16x32_bf16(a1.v, wf[dt][1], c, 0, 0, 0);
            const float pm0 = fmaxf(fmaxf(c[0], c[1]), 0.f);
            const float pm1 = fmaxf(fmaxf(c[2], c[3]), 0.f);
            const float add = pm0 + pm1;
            if (hi) sums1[dt] += add; else sums0[dt] += add;
        }
    }

    #pragma unroll
    for (int dt = 0; dt < 4; ++dt) {
        float v0 = sums0[dt], v1 = sums1[dt];
        v0 += __shfl_xor(v0, 16); v0 += __shfl_xor(v0, 32);
        v1 += __shfl_xor(v1, 16); v1 += __shfl_xor(v1, 32);
        sums0[dt] = v0; sums1[dt] = v1;
    }

    if (lane < 16) {
        const size_t row0 = (size_t)(b * NPq + npair * 2) * 64;
        #pragma unroll
        for (int dt = 0; dt < 4; ++dt) {
            const int d = dt * 16 + lane;
            float t0 = sums0[dt] * (1.0f / 36.0f);
            float t1 = sums1[dt] * (1.0f / 36.0f);
            float* p0 = sumFeat + row0 + d;
            float* p1 = sumFeat + row0 + 64 + d;
            if (accumulate) { t0 += *p0; t1 += *p1; }
            *p0 = t0; *p1 = t1;
        }
    }
}

// ---------------------------------------------------------------------------
// Phase 3: heads (verbatim — verified).  Block = (32 points, branch).
// ---------------------------------------------------------------------------
__global__ __launch_bounds__(256) void head_kernel(
    const float* __restrict__ sumFeat, const float invS,
    const float* __restrict__ fc_w,  const float* __restrict__ fc_b,
    const float* __restrict__ cls_w, const float* __restrict__ cls_b,
    const float* __restrict__ cls_ow, const float* __restrict__ cls_ob,
    const float* __restrict__ reg_w, const float* __restrict__ reg_b,
    const float* __restrict__ reg_ow, const float* __restrict__ reg_ob,
    const float* __restrict__ loc_w, const float* __restrict__ loc_b,
    const float* __restrict__ loc_ow, const float* __restrict__ loc_ob,
    float* __restrict__ out, float* __restrict__ xs_next)
{
    __shared__ __align__(16) float sAct0[32 * HSTR];
    __shared__ __align__(16) float sAct1[32 * HSTR];
    __shared__ __align__(16) float sW0[4096];
    __shared__ __align__(16) float sW1[4864];

    const int tid = threadIdx.x;
    const int hb  = blockIdx.x % 3;
    const int pg  = blockIdx.x / 3;
    const int p0  = pg * 32;
    const int tm  = tid >> 4;
    const int tn  = tid & 15;

    const float* h_w  = (hb == 0) ? cls_w  : (hb == 1) ? reg_w  : loc_w;
    const float* h_b  = (hb == 0) ? cls_b  : (hb == 1) ? reg_b  : loc_b;
    const float* h_ow = (hb == 0) ? cls_ow : (hb == 1) ? reg_ow : loc_ow;
    const float* h_ob = (hb == 0) ? cls_ob : (hb == 1) ? reg_ob : loc_ob;
    const int ow_n    = (hb == 0) ? 128    : (hb == 1) ? 64 * REGD : 64;

    #pragma unroll
    for (int i = 0; i < 4; ++i)
        *(float4*)&sW0[(i * 256 + tid) * 4] = *(const float4*)&fc_w[(i * 256 + tid) * 4];
    for (int idx = tid; idx < 32 * 64; idx += 256) {
        const int p = idx >> 6, c = idx & 63;
        sAct0[p * HSTR + c] = sumFeat[(size_t)(p0 + p) * 64 + c] * invS;
    }

    auto do_gemm = [&](const float* src, float* dst, const float* wbuf,
                       const float* gb, const float* nextw, int nextn,
                       float* nextbuf) {
        __syncthreads();
        float4 pf[5];
        const int n4 = nextn >> 2;
        #pragma unroll
        for (int i = 0; i < 5; ++i) {
            const int idx = i * 256 + tid;
            if (idx < n4) pf[i] = *(const float4*)&nextw[idx * 4];
        }
        const float4 b4 = *(const float4*)&gb[4 * tn];
        float4 acc0 = b4, acc1 = b4;
        const float* r0 = src + (2 * tm) * HSTR;
        const float* r1 = r0 + HSTR;
        #pragma unroll 4
        for (int k4 = 0; k4 < 16; ++k4) {
            const float4 a0 = *(const float4*)&r0[4 * k4];
            const float4 a1 = *(const float4*)&r1[4 * k4];
            const float4 w0 = *(const float4*)&wbuf[(4 * k4 + 0) * 64 + 4 * tn];
            const float4 w1 = *(const float4*)&wbuf[(4 * k4 + 1) * 64 + 4 * tn];
            const float4 w2 = *(const float4*)&wbuf[(4 * k4 + 2) * 64 + 4 * tn];
            const float4 w3 = *(const float4*)&wbuf[(4 * k4 + 3) * 64 + 4 * tn];
            acc0.x += a0.x*w0.x + a0.y*w1.x + a0.z*w2.x + a0.w*w3.x;
            acc0.y += a0.x*w0.y + a0.y*w1.y + a0.z*w2.y + a0.w*w3.y;
            acc0.z += a0.x*w0.z + a0.y*w1.z + a0.z*w2.z + a0.w*w3.z;
            acc0.w += a0.x*w0.w + a0.y*w1.w + a0.z*w2.w + a0.w*w3.w;
            acc1.x += a1.x*w0.x + a1.y*w1.x + a1.z*w2.x + a1.w*w3.x;
            acc1.y += a1.x*w0.y + a1.y*w1.y + a1.z*w2.y + a1.w*w3.y;
            acc1.z += a1.x*w0.z + a1.y*w1.z + a1.z*w2.z + a1.w*w3.z;
            acc1.w += a1.x*w0.w + a1.y*w1.w + a1.z*w2.w + a1.w*w3.w;
        }
        float4 v0, v1;
        v0.x = fmaxf(acc0.x, 0.f); v0.y = fmaxf(acc0.y, 0.f);
        v0.z = fmaxf(acc0.z, 0.f); v0.w = fmaxf(acc0.w, 0.f);
        v1.x = fmaxf(acc1.x, 0.f); v1.y = fmaxf(acc1.y, 0.f);
        v1.z = fmaxf(acc1.z, 0.f); v1.w = fmaxf(acc1.w, 0.f);
        *(float4*)&dst[(2 * tm) * HSTR + 4 * tn]     = v0;
        *(float4*)&dst[(2 * tm + 1) * HSTR + 4 * tn] = v1;
        #pragma unroll
        for (int i = 0; i < 5; ++i) {
            const int idx = i * 256 + tid;
            if (idx < n4) *(float4*)&nextbuf[idx * 4] = pf[i];
        }
    };

    do_gemm(sAct0, sAct1, sW0, fc_b,      h_w,        4096, sW1);
    do_gemm(sAct1, sAct0, sW1, h_b,       h_w + 4096, 4096, sW0);
    do_gemm(sAct0, sAct1, sW0, h_b + 64,  h_ow,       ow_n, sW1);
    __syncthreads();

    if (hb == 0) {
        if (tid < 64) {
            const int p = tid >> 1, d = tid & 1;
            const float* row = &sAct1[p * HSTR];
            float z = h_ob[d];
            #pragma unroll 4
            for (int k4 = 0; k4 < 16; ++k4) {
                const float4 a = *(const float4*)&row[4 * k4];
                z += a.x * sW1[(4 * k4 + 0) * 2 + d] + a.y * sW1[(4 * k4 + 1) * 2 + d]
                   + a.z * sW1[(4 * k4 + 2) * 2 + d] + a.w * sW1[(4 * k4 + 3) * 2 + d];
            }
            out[(size_t)(p0 + p) * OUTD + d] = z;
        }
    } else if (hb == 1) {
        const int p  = tid & 31;
        const int jg = tid >> 5;
        const float* row = &sAct1[p * HSTR];
        float* orow = out + (size_t)(p0 + p) * OUTD;
        float* xsp  = xs_next + (size_t)(p0 + p) * NOq;
        for (int j = jg; j < REGD; j += 8) {
            float z = h_ob[j];
            #pragma unroll 4
            for (int k4 = 0; k4 < 16; ++k4) {
                const float4 a = *(const float4*)&row[4 * k4];
                z += a.x * sW1[(4 * k4 + 0) * REGD + j] + a.y * sW1[(4 * k4 + 1) * REGD + j]
                   + a.z * sW1[(4 * k4 + 2) * REGD + j] + a.w * sW1[(4 * k4 + 3) * REGD + j];
            }
            orow[2 + j] = z;
            if (j >= 4) xsp[j - 4] = 1.0f / (1.0f + __expf(-z));
        }
    } else {
        if (tid < 32) {
            const float* row = &sAct1[tid * HSTR];
            float z = h_ob[0];
            #pragma unroll 4
            for (int k4 = 0; k4 < 16; ++k4) {
                const float4 a = *(const float4*)&row[4 * k4];
                z += a.x * sW1[4 * k4] + a.y * sW1[4 * k4 + 1]
                   + a.z * sW1[4 * k4 + 2] + a.w * sW1[4 * k4 + 3];
            }
            out[(size_t)(p0 + tid) * OUTD + 78] = z;
        }
    }
}

// ---------------------------------------------------------------------------
extern "C" void kernel_launch(void* const* d_in, const int* in_sizes, int n_in,
                              void* d_out, int out_size, void* d_ws, size_t ws_size,
                              hipStream_t stream)
{
    const float* x0        = (const float*)d_in[0];
    const float* x1        = (const float*)d_in[1];
    const float* x2        = (const float*)d_in[2];
    const float* prior_xs0 = (const float*)d_in[3];
    const float* l_weight  = (const float*)d_in[4];
    const float* lsgi_w    = (const float*)d_in[5];
    const float* fc_w      = (const float*)d_in[6];
    const float* fc_b      = (const float*)d_in[7];
    const float* cls_w     = (const float*)d_in[8];
    const float* cls_b     = (const float*)d_in[9];
    const float* cls_ow    = (const float*)d_in[10];
    const float* cls_ob    = (const float*)d_in[11];
    const float* reg_w     = (const float*)d_in[12];
    const float* reg_b     = (const float*)d_in[13];
    const float* reg_ow    = (const float*)d_in[14];
    const float* reg_ob    = (const float*)d_in[15];
    const float* loc_w     = (const float*)d_in[16];
    const float* loc_b     = (const float*)d_in[17];
    const float* loc_ow    = (const float*)d_in[18];
    const float* loc_ob    = (const float*)d_in[19];

    float* out     = (float*)d_out;
    float* sumFeat = (float*)d_ws;                               // [6144][64] f32
    float* xs      = sumFeat + (size_t)Bq * NPq * Cq;            // [6144][72] f32
    unsigned short* tab0 = (unsigned short*)(xs + (size_t)Bq * PTS);
    unsigned short* tab1 = tab0 + (size_t)Bq * NOq * 26  * 64;   // W=25
    unsigned short* tab2 = tab1 + (size_t)Bq * NOq * 51  * 64;   // W=50
    // tab2 size: Bq*NOq*101*64                                   // W=100

    hipLaunchKernelGGL(build_tables_kernel, dim3(3 * Bq * NOq), dim3(256), 0, stream,
                       x2, x1, x0, l_weight, tab0, tab1, tab2);

    for (int s = 0; s < 3; ++s) {
        const float* xsrc = (s == 0) ? prior_xs0 : xs;
        const int xstr    = (s == 0) ? 0 : PTS;
        if (s == 0)
            hipLaunchKernelGGL((fused_pool_kernel<25>), dim3(Bq * 24), dim3(256), 0, stream,
                               tab0, xsrc, xstr, lsgi_w + s * 4096, sumFeat, 0);
        else if (s == 1)
            hipLaunchKernelGGL((fused_pool_kernel<50>), dim3(Bq * 24), dim3(256), 0, stream,
                               tab1, xsrc, xstr, lsgi_w + s * 4096, sumFeat, 1);
        else
            hipLaunchKernelGGL((fused_pool_kernel<100>), dim3(Bq * 24), dim3(256), 0, stream,
                               tab2, xsrc, xstr, lsgi_w + s * 4096, sumFeat, 1);

        hipLaunchKernelGGL(head_kernel, dim3((Bq * NPq / 32) * 3), dim3(256), 0, stream,
                           sumFeat, 1.0f / (float)(s + 1),
                           fc_w, fc_b, cls_w, cls_b, cls_ow, cls_ob,
                           reg_w, reg_b, reg_ow, reg_ob,
                           loc_w, loc_b, loc_ow, loc_ob,
                           out + (size_t)s * Bq * NPq * OUTD, xs);
    }
}

// Round 9
// 259.474 us; speedup vs baseline: 1.0968x; 1.0776x over previous
//
#include <hip/hip_runtime.h>
#include <hip/hip_bf16.h>

#define Bq   32
#define Cq   64
#define NPq  192
#define NOq  72
#define PTS  (NPq * NOq)   // 13824
#define REGD 76
#define OUTD 79

typedef __attribute__((ext_vector_type(8))) short short8;
typedef __attribute__((ext_vector_type(4))) float float4v;

__device__ inline unsigned short f2bf(float x) {
    __hip_bfloat16 h = __float2bfloat16(x);
    return *reinterpret_cast<unsigned short*>(&h);
}
__device__ inline float bf2f(unsigned short u) {
    unsigned int x = ((unsigned int)u) << 16;
    float f;
    __builtin_memcpy(&f, &x, 4);
    return f;
}

// ---------------------------------------------------------------------------
// Phase 0 (once): build gated y-blended tables for ALL 3 stages.
// tab[s][b][o][x][c] bf16, x in [0..W] (x=W replicates W-1), c innermost.
// o-major block index (o*96 + s*32+b) keeps each (s,b)'s blocks on one XCD.
// Templated on <H,W> so index math is magic-mul, not integer division.
// ---------------------------------------------------------------------------
template<int H, int W>
__device__ __forceinline__ void build_one(
    const float* __restrict__ feat, unsigned short* __restrict__ tab,
    const float* __restrict__ lw, const int b, const int o,
    float* __restrict__ sRow, const int tid)
{
    constexpr int Wp = W + 1;

    const float ys = 1.0f - (float)o * (1.0f / 71.0f);
    const float iy = ys * (float)(H - 1);
    const float fy = floorf(iy);
    const float wy = iy - fy;
    int iy0 = (int)fy; iy0 = iy0 < 0 ? 0 : (iy0 > H - 1 ? H - 1 : iy0);
    const int iy1 = (iy0 + 1 > H - 1) ? H - 1 : iy0 + 1;
    const float gate = 1.0f / (1.0f + __expf(-lw[o]));

    const float* fb = feat + (size_t)b * 64 * H * W;
    const int iy0W = iy0 * W, iy1W = iy1 * W;

    // blend rows -> LDS [c][x] fp32 (compile-time W: div -> magic mul)
    constexpr int tot = 64 * W;
    for (int idx = tid; idx < tot; idx += 256) {
        const int c = idx / W;
        const int x = idx - c * W;
        const float* f = fb + c * (H * W);
        sRow[c * Wp + x] = ((1.0f - wy) * f[iy0W + x] + wy * f[iy1W + x]) * gate;
    }
    __syncthreads();

    // write transposed [x][c] bf16, 2 channels packed per 32-bit store
    unsigned int* to = (unsigned int*)(tab + (size_t)(b * NOq + o) * Wp * 64);
    constexpr int tot2 = Wp * 32;
    for (int idx = tid; idx < tot2; idx += 256) {
        const int x  = idx >> 5;
        const int c0 = (idx & 31) * 2;
        const int xx = (x < W) ? x : (W - 1);
        const unsigned int lo = f2bf(sRow[c0 * Wp + xx]);
        const unsigned int hi = f2bf(sRow[(c0 + 1) * Wp + xx]);
        to[x * 32 + (c0 >> 1)] = lo | (hi << 16);
    }
}

__global__ __launch_bounds__(256) void build_tables_kernel(
    const float* __restrict__ f0,   // x2: H=10,W=25
    const float* __restrict__ f1,   // x1: H=20,W=50
    const float* __restrict__ f2,   // x0: H=40,W=100
    const float* __restrict__ lw,
    unsigned short* __restrict__ t0,
    unsigned short* __restrict__ t1,
    unsigned short* __restrict__ t2)
{
    __shared__ float sRow[64 * 101];
    const int tid = threadIdx.x;
    const int o   = blockIdx.x / 96;
    const int sb  = blockIdx.x - o * 96;
    const int s   = sb >> 5;
    const int b   = sb & 31;

    if (s == 0)      build_one<10, 25 >(f0, t0, lw, b, o, sRow, tid);
    else if (s == 1) build_one<20, 50 >(f1, t1, lw, b, o, sRow, tid);
    else             build_one<40, 100>(f2, t2, lw, b, o, sRow, tid);
}

// ---------------------------------------------------------------------------
// Fused: table gather + x-lerp + MFMA + relu/pairmax/mean + FULL HEAD.
// Block = (b, group of 8 n), grid 768, block index ng*32+b (XCD locality).
// Pool epilogue stashes the 8 fused rows in LDS, then the block runs
// fc -> {cls,reg,loc} 2-layer MLPs + projections for its 8 points.
// ---------------------------------------------------------------------------
template<int W>
__global__ __launch_bounds__(256) void fused_pool_head_kernel(
    const unsigned short* __restrict__ tab,   // [B][72][W+1][64] bf16
    const float* __restrict__ xsrc, const int xstride,
    const float* __restrict__ lsgi,           // [64][64] this stage
    float* __restrict__ sumFeat,              // [B*NP][64]
    const int stage,
    const float* __restrict__ fc_w,  const float* __restrict__ fc_b,
    const float* __restrict__ cls_w, const float* __restrict__ cls_b,
    const float* __restrict__ cls_ow, const float* __restrict__ cls_ob,
    const float* __restrict__ reg_w, const float* __restrict__ reg_b,
    const float* __restrict__ reg_ow, const float* __restrict__ reg_ob,
    const float* __restrict__ loc_w, const float* __restrict__ loc_b,
    const float* __restrict__ loc_ow, const float* __restrict__ loc_ob,
    float* __restrict__ out, float* __restrict__ xs_next)
{
    constexpr int Wp = W + 1;
    __shared__ __align__(16) float sF [8][68];
    __shared__ __align__(16) float sC [8][68];
    __shared__ __align__(16) float sT1[8][68];
    __shared__ __align__(16) float sT2[8][68];
    __shared__ __align__(16) float sWt[4864];

    const int tid  = threadIdx.x;
    const int w    = tid >> 6;
    const int lane = tid & 63;
    const int ng   = blockIdx.x >> 5;         // 0..23
    const int b    = blockIdx.x & 31;
    const int npair = ng * 4 + w;             // 0..95

    // ---------------- pool (verbatim from R8) ----------------
    short8 wf[4][2];
    {
        const int kb = ((lane >> 4) & 3) * 8;
        const int dl = lane & 15;
        #pragma unroll
        for (int ks = 0; ks < 2; ++ks)
            #pragma unroll
            for (int dt = 0; dt < 4; ++dt) {
                union { unsigned short u[8]; short8 v; } pk;
                #pragma unroll
                for (int j = 0; j < 8; ++j)
                    pk.u[j] = f2bf(lsgi[(ks * 32 + kb + j) * 64 + dt * 16 + dl]);
                wf[dt][ks] = pk.v;
            }
    }

    const unsigned short* tb = tab + (size_t)b * NOq * Wp * 64;
    const float* xp = xsrc + (size_t)xstride * b;
    const int m  = lane & 15;
    const int kg = lane >> 4;
    const int nt0 = npair * 9;

    float sums0[4] = {0.f, 0.f, 0.f, 0.f};
    float sums1[4] = {0.f, 0.f, 0.f, 0.f};

    #pragma unroll
    for (int ntl = 0; ntl < 9; ++ntl) {
        const int pt = (nt0 + ntl) * 16 + m;
        const int o  = pt % NOq;
        float ixf = xp[pt] * (float)(W - 1);
        ixf = fminf(fmaxf(ixf, 0.0f), (float)(W - 1));
        const float fx = floorf(ixf);
        const float wx = ixf - fx;
        const int ix0 = (int)fx;

        const unsigned short* col = tb + ((size_t)o * Wp + ix0) * 64 + kg * 8;
        union { unsigned short u[8]; short8 v; } t00, t01, t10, t11, a0, a1;
        t00.v = *(const short8*)(col);
        t01.v = *(const short8*)(col + 64);
        t10.v = *(const short8*)(col + 32);
        t11.v = *(const short8*)(col + 96);
        #pragma unroll
        for (int j = 0; j < 8; ++j) {
            const float l0 = bf2f(t00.u[j]), h0 = bf2f(t01.u[j]);
            const float l1 = bf2f(t10.u[j]), h1 = bf2f(t11.u[j]);
            a0.u[j] = f2bf(l0 + wx * (h0 - l0));
            a1.u[j] = f2bf(l1 + wx * (h1 - l1));
        }

        const bool hi = (ntl * 16 + (kg * 4)) >= NOq;
        #pragma unroll
        for (int dt = 0; dt < 4; ++dt) {
            float4v c = {0.f, 0.f, 0.f, 0.f};
            c = __builtin_amdgcn_mfma_f32_16x16x32_bf16(a0.v, wf[dt][0], c, 0, 0, 0);
            c = __builtin_amdgcn_mfma_f32_16x16x32_bf16(a1.v, wf[dt][1], c, 0, 0, 0);
            const float pm0 = fmaxf(fmaxf(c[0], c[1]), 0.f);
            const float pm1 = fmaxf(fmaxf(c[2], c[3]), 0.f);
            const float add = pm0 + pm1;
            if (hi) sums1[dt] += add; else sums0[dt] += add;
        }
    }

    #pragma unroll
    for (int dt = 0; dt < 4; ++dt) {
        float v0 = sums0[dt], v1 = sums1[dt];
        v0 += __shfl_xor(v0, 16); v0 += __shfl_xor(v0, 32);
        v1 += __shfl_xor(v1, 16); v1 += __shfl_xor(v1, 32);
        sums0[dt] = v0; sums1[dt] = v1;
    }

    const float invS = 1.0f / (float)(stage + 1);
    if (lane < 16) {
        const size_t row0 = (size_t)(b * NPq + npair * 2) * 64;
        #pragma unroll
        for (int dt = 0; dt < 4; ++dt) {
            const int d = dt * 16 + lane;
            float t0 = sums0[dt] * (1.0f / 36.0f);
            float t1 = sums1[dt] * (1.0f / 36.0f);
            float* p0 = sumFeat + row0 + d;
            float* p1 = sumFeat + row0 + 64 + d;
            if (stage > 0) { t0 += *p0; t1 += *p1; }
            *p0 = t0; *p1 = t1;
            sF[2 * w][d]     = t0 * invS;       // fused rows for the head
            sF[2 * w + 1][d] = t1 * invS;
        }
    }

    // ---------------- head (8 points, in-block) ----------------
    const int pt2 = tid >> 5;          // 0..7 local point
    const int dh  = tid & 31;
    const int d0  = dh * 2;
    const int p0g = b * NPq + ng * 8;  // global point base

    // one 64->64 relu layer: dst[pt][d] = relu(b[d] + sum_k src[pt][k]*w[k][d])
    auto gemm64 = [&](const float (*src)[68], float (*dst)[68],
                      const float* __restrict__ gw, const float* __restrict__ gb) {
        __syncthreads();                       // sWt free, src ready
        #pragma unroll
        for (int i = 0; i < 4; ++i)
            *(float4*)&sWt[(i * 256 + tid) * 4] = *(const float4*)&gw[(i * 256 + tid) * 4];
        __syncthreads();
        float a0 = gb[d0], a1 = gb[d0 + 1];
        #pragma unroll 8
        for (int k = 0; k < 64; ++k) {
            const float av = src[pt2][k];
            const float2 w2 = *(const float2*)&sWt[k * 64 + d0];
            a0 += av * w2.x; a1 += av * w2.y;
        }
        dst[pt2][d0]     = fmaxf(a0, 0.f);
        dst[pt2][d0 + 1] = fmaxf(a1, 0.f);
    };

    gemm64(sF, sC, fc_w, fc_b);

    // ---- cls ----
    gemm64(sC,  sT1, cls_w,        cls_b);
    gemm64(sT1, sT2, cls_w + 4096, cls_b + 64);
    __syncthreads();
    if (tid < 16) {
        const int p = tid >> 1, d = tid & 1;
        float z = cls_ob[d];
        #pragma unroll 8
        for (int k = 0; k < 64; ++k) z += sT2[p][k] * cls_ow[k * 2 + d];
        out[(size_t)(p0g + p) * OUTD + d] = z;
    }

    // ---- reg ----
    gemm64(sC,  sT1, reg_w,        reg_b);
    gemm64(sT1, sT2, reg_w + 4096, reg_b + 64);
    __syncthreads();                           // sWt reads done
    for (int idx = tid; idx < 64 * REGD; idx += 256) sWt[idx] = reg_ow[idx];
    __syncthreads();
    {
        float* orow = out + (size_t)(p0g + pt2) * OUTD;
        float* xsp  = xs_next + (size_t)(p0g + pt2) * NOq;
        for (int j = dh; j < REGD; j += 32) {
            float z = reg_ob[j];
            #pragma unroll 8
            for (int k = 0; k < 64; ++k) z += sT2[pt2][k] * sWt[k * REGD + j];
            orow[2 + j] = z;
            if (j >= 4) xsp[j - 4] = 1.0f / (1.0f + __expf(-z));
        }
    }

    // ---- loc ----
    gemm64(sC,  sT1, loc_w,        loc_b);
    gemm64(sT1, sT2, loc_w + 4096, loc_b + 64);
    __syncthreads();
    if (tid < 8) {
        float z = loc_ob[0];
        #pragma unroll 8
        for (int k = 0; k < 64; ++k) z += sT2[tid][k] * loc_ow[k];
        out[(size_t)(p0g + tid) * OUTD + 78] = z;
    }
}

// ---------------------------------------------------------------------------
extern "C" void kernel_launch(void* const* d_in, const int* in_sizes, int n_in,
                              void* d_out, int out_size, void* d_ws, size_t ws_size,
                              hipStream_t stream)
{
    const float* x0        = (const float*)d_in[0];
    const float* x1        = (const float*)d_in[1];
    const float* x2        = (const float*)d_in[2];
    const float* prior_xs0 = (const float*)d_in[3];
    const float* l_weight  = (const float*)d_in[4];
    const float* lsgi_w    = (const float*)d_in[5];
    const float* fc_w      = (const float*)d_in[6];
    const float* fc_b      = (const float*)d_in[7];
    const float* cls_w     = (const float*)d_in[8];
    const float* cls_b     = (const float*)d_in[9];
    const float* cls_ow    = (const float*)d_in[10];
    const float* cls_ob    = (const float*)d_in[11];
    const float* reg_w     = (const float*)d_in[12];
    const float* reg_b     = (const float*)d_in[13];
    const float* reg_ow    = (const float*)d_in[14];
    const float* reg_ob    = (const float*)d_in[15];
    const float* loc_w     = (const float*)d_in[16];
    const float* loc_b     = (const float*)d_in[17];
    const float* loc_ow    = (const float*)d_in[18];
    const float* loc_ob    = (const float*)d_in[19];

    float* out     = (float*)d_out;
    float* sumFeat = (float*)d_ws;                               // [6144][64] f32
    float* xs      = sumFeat + (size_t)Bq * NPq * Cq;            // [6144][72] f32
    unsigned short* tab0 = (unsigned short*)(xs + (size_t)Bq * PTS);
    unsigned short* tab1 = tab0 + (size_t)Bq * NOq * 26  * 64;   // W=25
    unsigned short* tab2 = tab1 + (size_t)Bq * NOq * 51  * 64;   // W=50

    hipLaunchKernelGGL(build_tables_kernel, dim3(3 * Bq * NOq), dim3(256), 0, stream,
                       x2, x1, x0, l_weight, tab0, tab1, tab2);

    for (int s = 0; s < 3; ++s) {
        const float* xsrc = (s == 0) ? prior_xs0 : xs;
        const int xstr    = (s == 0) ? 0 : PTS;
        const unsigned short* tb = (s == 0) ? tab0 : (s == 1) ? tab1 : tab2;
        float* outS = out + (size_t)s * Bq * NPq * OUTD;
        if (s == 0)
            hipLaunchKernelGGL((fused_pool_head_kernel<25>), dim3(Bq * 24), dim3(256), 0, stream,
                               tb, xsrc, xstr, lsgi_w + s * 4096, sumFeat, s,
                               fc_w, fc_b, cls_w, cls_b, cls_ow, cls_ob,
                               reg_w, reg_b, reg_ow, reg_ob,
                               loc_w, loc_b, loc_ow, loc_ob, outS, xs);
        else if (s == 1)
            hipLaunchKernelGGL((fused_pool_head_kernel<50>), dim3(Bq * 24), dim3(256), 0, stream,
                               tb, xsrc, xstr, lsgi_w + s * 4096, sumFeat, s,
                               fc_w, fc_b, cls_w, cls_b, cls_ow, cls_ob,
                               reg_w, reg_b, reg_ow, reg_ob,
                               loc_w, loc_b, loc_ow, loc_ob, outS, xs);
        else
            hipLaunchKernelGGL((fused_pool_head_kernel<100>), dim3(Bq * 24), dim3(256), 0, stream,
                               tb, xsrc, xstr, lsgi_w + s * 4096, sumFeat, s,
                               fc_w, fc_b, cls_w, cls_b, cls_ow, cls_ob,
                               reg_w, reg_b, reg_ow, reg_ob,
                               loc_w, loc_b, loc_ow, loc_ob, outS, xs);
    }
}